// Round 1
// 161.441 us; speedup vs baseline: 1.1777x; 1.1777x over previous
//
#include <hip/hip_runtime.h>
#include <hip/hip_fp16.h>
#include <math.h>

#define NFEAT 128
#define NCLS  64
#define RQ8   8             // uint4 per fp16 64-wide row (128 B)
#define WSTR  132           // W LDS row stride in halves
#define NBLK  256           // grid for edge-stream passes

// ---------- helpers ----------

typedef _Float16 h2v __attribute__((ext_vector_type(2)));

__device__ __forceinline__ float dot2acc(unsigned int hv, unsigned int wv, float c) {
#if __has_builtin(__builtin_amdgcn_fdot2)
    union { unsigned int u; h2v v; } a, bq; a.u = hv; bq.u = wv;
    return __builtin_amdgcn_fdot2(a.v, bq.v, c, false);
#else
    union { unsigned int u; __half2 h; } a, bq; a.u = hv; bq.u = wv;
    float2 fa = __half22float2(a.h), fb = __half22float2(bq.h);
    return fmaf(fa.x, fb.x, fmaf(fa.y, fb.y, c));
#endif
}

// packed fp16 accumulate: 4 v_pk_add_f16 per 16B row-chunk
__device__ __forceinline__ void acc4(__half2 a[4], uint4 v) {
    union { uint4 u; __half2 h[4]; } c; c.u = v;
    a[0] = __hadd2(a[0], c.h[0]); a[1] = __hadd2(a[1], c.h[1]);
    a[2] = __hadd2(a[2], c.h[2]); a[3] = __hadd2(a[3], c.h[3]);
}

__device__ __forceinline__ __half2 red8(__half2 a) {   // reduce across 8 sub-slots
    union { __half2 h; int i; } u, v;
    u.h = a; v.i = __shfl_xor(u.i, 8);  a = __hadd2(a, v.h);
    u.h = a; v.i = __shfl_xor(u.i, 16); a = __hadd2(a, v.h);
    u.h = a; v.i = __shfl_xor(u.i, 32); a = __hadd2(a, v.h);
    return a;
}

// ---------- build pass 1: 256-node-bucket histogram only ----------
__global__ __launch_bounds__(256) void hist_kernel(const int* __restrict__ dst,
                                                   int* __restrict__ h,
                                                   int E4, int E, int nb) {
    __shared__ int lh[256];
    const int tid = threadIdx.x;
    lh[tid] = 0;
    __syncthreads();
    for (int idx = blockIdx.x * 256 + tid; idx < E4; idx += NBLK * 256) {
        int base = idx * 4;
        if (base + 3 < E) {
            int4 d = ((const int4*)dst)[idx];
            atomicAdd(&lh[d.x >> 8], 1); atomicAdd(&lh[d.y >> 8], 1);
            atomicAdd(&lh[d.z >> 8], 1); atomicAdd(&lh[d.w >> 8], 1);
        } else {
            for (int e = base; e < E; ++e) atomicAdd(&lh[dst[e] >> 8], 1);
        }
    }
    __syncthreads();
    if (tid < nb) h[blockIdx.x * nb + tid] = lh[tid];
}

// pass 2a: per bucket, exclusive scan over its 256 block-counts + total
__global__ __launch_bounds__(256) void colscan_kernel(int* __restrict__ h,
                                                      int* __restrict__ btot, int nb) {
    __shared__ int lds[256];
    const int tid = threadIdx.x;
    const int B = blockIdx.x;
    int v = h[tid * nb + B];
    lds[tid] = v;
    __syncthreads();
    for (int off = 1; off < 256; off <<= 1) {
        int t = (tid >= off) ? lds[tid - off] : 0;
        __syncthreads();
        lds[tid] += t;
        __syncthreads();
    }
    h[tid * nb + B] = lds[tid] - v;                // exclusive within bucket
    if (tid == 255) btot[B] = lds[255];
}

// pass 2b: exclusive scan of bucket totals -> bbase[0..nb]
__global__ __launch_bounds__(256) void bucket_scan_kernel(const int* __restrict__ btot,
                                                          int* __restrict__ bbase, int nb) {
    __shared__ int lds[256];
    const int tid = threadIdx.x;
    int v = (tid < nb) ? btot[tid] : 0;
    lds[tid] = v;
    __syncthreads();
    for (int off = 1; off < 256; off <<= 1) {
        int t = (tid >= off) ? lds[tid - off] : 0;
        __syncthreads();
        lds[tid] += t;
        __syncthreads();
    }
    if (tid < nb) bbase[tid + 1] = lds[tid];
    if (tid == 0) bbase[0] = 0;
}

// pass 3: replay edges, write (src,dst) pairs into bucket-ordered COO
__global__ __launch_bounds__(256) void bucket_scatter_kernel(const int* __restrict__ src,
                                                             const int* __restrict__ dst,
                                                             const int* __restrict__ h,
                                                             const int* __restrict__ bbase,
                                                             int2* __restrict__ bedg,
                                                             int E4, int E, int nb) {
    __shared__ int cur[256];
    const int tid = threadIdx.x;
    if (tid < nb) cur[tid] = bbase[tid] + h[blockIdx.x * nb + tid];
    __syncthreads();
    for (int idx = blockIdx.x * 256 + tid; idx < E4; idx += NBLK * 256) {
        int base = idx * 4;
        if (base + 3 < E) {
            int4 s = ((const int4*)src)[idx];
            int4 d = ((const int4*)dst)[idx];
            int p;
            p = atomicAdd(&cur[d.x >> 8], 1); bedg[p] = make_int2(s.x, d.x);
            p = atomicAdd(&cur[d.y >> 8], 1); bedg[p] = make_int2(s.y, d.y);
            p = atomicAdd(&cur[d.z >> 8], 1); bedg[p] = make_int2(s.z, d.z);
            p = atomicAdd(&cur[d.w >> 8], 1); bedg[p] = make_int2(s.w, d.w);
        } else {
            for (int e = base; e < E; ++e) {
                int p = atomicAdd(&cur[dst[e] >> 8], 1);
                bedg[p] = make_int2(src[e], dst[e]);
            }
        }
    }
}

// pass 4: per-bucket LDS counting sort -> csr rows (padded x8, pads = N),
// rbeg/rend, dinv. Per-bucket csr slack: +1792 (256 rows x up to 7 pads).
__global__ __launch_bounds__(256) void drain_kernel(const int2* __restrict__ bedg,
                                                    const int* __restrict__ bbase,
                                                    int* __restrict__ csr,
                                                    int* __restrict__ rbeg,
                                                    int* __restrict__ rend,
                                                    float* __restrict__ dinv, int N) {
    __shared__ int lcnt[256];
    __shared__ int lds[256];
    __shared__ int loc[256];
    const int B = blockIdx.x;
    const int tid = threadIdx.x;
    const int s0 = bbase[B], s1 = bbase[B + 1];

    lcnt[tid] = 0;
    __syncthreads();
    for (int e = s0 + tid; e < s1; e += 256)
        atomicAdd(&lcnt[bedg[e].y & 255], 1);
    __syncthreads();

    const int c = lcnt[tid];
    const int cp = (c + 7) & ~7;                   // padded row length (x8 for 8-sub gather)
    lds[tid] = cp;
    __syncthreads();
    for (int off = 1; off < 256; off <<= 1) {      // exclusive scan of padded lens
        int t = (tid >= off) ? lds[tid - off] : 0;
        __syncthreads();
        lds[tid] += t;
        __syncthreads();
    }
    const int base = bbase[B] + 1792 * B;          // per-bucket csr slack: +1792
    loc[tid] = base + lds[tid] - cp;               // row start
    __syncthreads();
    lcnt[tid] = loc[tid];                          // reuse as cursor
    __syncthreads();

    for (int e = s0 + tid; e < s1; e += 256) {
        int2 Ev = bedg[e];
        int p = atomicAdd(&lcnt[Ev.y & 255], 1);
        csr[p] = Ev.x;
    }
    __syncthreads();

    int i = B * 256 + tid;
    if (i < N) {
        int start = loc[tid], end = start + cp;
        for (int p = lcnt[tid]; p < end; ++p) csr[p] = N;   // <=7 pads (dummy row)
        rbeg[i] = start; rend[i] = end;
        dinv[i] = rsqrtf((float)c + 1.0f);         // +1 self-loop
    }
}

// ---------- projection first (SGC linearity): zh = fp16(dinv_i * (x_i @ W^T)) ----------
// Replaces old prep+cls input path: reads fp32 x directly, converts to fp16 in LDS,
// fp32-accumulated fdot2, dinv folded into epilogue. Also zeroes dummy rows N of zh,y1h.
__global__ __launch_bounds__(512) void gemm_kernel(const float* __restrict__ x,
                                                   const float* __restrict__ W,
                                                   const float* __restrict__ dinv,
                                                   __half* __restrict__ zh,
                                                   __half* __restrict__ y1h, int N) {
    __shared__ __half Wl[NCLS * WSTR];
    __shared__ __align__(16) __half HT[64][NFEAT];

    const int tid = threadIdx.x;
    const int w = tid >> 6, lane = tid & 63;

    if (blockIdx.x == 0 && tid < 32) {             // zero dummy rows (row N, 16 uint2 each)
        if (tid < 16) ((uint2*)zh)[(size_t)N * 16 + tid] = uint2{0u, 0u};
        else          ((uint2*)y1h)[(size_t)N * 16 + (tid - 16)] = uint2{0u, 0u};
    }

    for (int e = tid; e < NCLS * NFEAT; e += 512) {
        int r = e >> 7, c = e & 127;
        Wl[r * WSTR + c] = __float2half(W[e]);
    }
    {
        const float4* srcf = (const float4*)(x + (size_t)blockIdx.x * 64 * NFEAT);
        uint2* dh = (uint2*)&HT[0][0];
        const int row0 = blockIdx.x * 64;
        #pragma unroll
        for (int t = 0; t < 4; ++t) {
            int e = tid + 512 * t;                 // float4 index, 2048 total (32 per row)
            float4 f = (row0 + (e >> 5) < N) ? srcf[e] : float4{0.f, 0.f, 0.f, 0.f};
            union { uint2 u; __half2 h[2]; } r;
            r.h[0] = __floats2half2_rn(f.x, f.y);
            r.h[1] = __floats2half2_rn(f.z, f.w);
            dh[e] = r.u;
        }
    }
    __syncthreads();

    unsigned int wreg[64];
    {
        const uint2* wr = (const uint2*)&Wl[lane * WSTR];
        #pragma unroll
        for (int t = 0; t < 32; ++t) {
            uint2 v = wr[t];
            wreg[2 * t] = v.x; wreg[2 * t + 1] = v.y;
        }
    }

    #pragma unroll 1
    for (int r = 0; r < 8; ++r) {
        int node = blockIdx.x * 64 + w * 8 + r;
        if (node >= N) break;
        const unsigned int* hrow = (const unsigned int*)&HT[w * 8 + r][0];
        float dot = 0.f;
        #pragma unroll
        for (int t = 0; t < 64; ++t)
            dot = dot2acc(hrow[t], wreg[t], dot);
        zh[(size_t)node * NCLS + lane] = __float2half(dinv[node] * dot);
    }
}

// ---------- gather core: 64-wide rows, 8 subs x 8 q, 32-edge main loop ----------
__device__ __forceinline__ void gather_row64(__half2 a[4], const uint4* __restrict__ X,
                                             const int* __restrict__ csr,
                                             int ks, int ke, int sub, int q, int Nd) {
    int k = ks;
    int j0, j1, j2, j3;
    bool have = (k + 32 <= ke);
    if (have) {
        j0 = csr[k + sub];      j1 = csr[k + 8 + sub];
        j2 = csr[k + 16 + sub]; j3 = csr[k + 24 + sub];
    }
    while (have) {
        uint4 v0 = X[(size_t)j0 * RQ8 + q];
        uint4 v1 = X[(size_t)j1 * RQ8 + q];
        uint4 v2 = X[(size_t)j2 * RQ8 + q];
        uint4 v3 = X[(size_t)j3 * RQ8 + q];
        k += 32;
        have = (k + 32 <= ke);
        if (have) {                               // prefetch next indices
            j0 = csr[k + sub];      j1 = csr[k + 8 + sub];
            j2 = csr[k + 16 + sub]; j3 = csr[k + 24 + sub];
        }
        acc4(a, v0); acc4(a, v1); acc4(a, v2); acc4(a, v3);
    }
    int rem = (ke - k) >> 3;                      // 0..3 rounds of 8, wave-uniform
    if (rem) {
        int t0 = csr[k + sub];
        int t1 = csr[k + 8 + sub];      // overrun reads land in bucket slack (garbage)
        int t2 = csr[k + 16 + sub];     // but are discarded via redirect below
        if (rem < 2) t1 = Nd;
        if (rem < 3) t2 = Nd;
        uint4 v0 = X[(size_t)t0 * RQ8 + q];
        uint4 v1 = X[(size_t)t1 * RQ8 + q];
        uint4 v2 = X[(size_t)t2 * RQ8 + q];
        acc4(a, v0); acc4(a, v1); acc4(a, v2);
    }
}

// ---------- hop1: out[i] = fp16( dinv_i^2 * (sum_j in[j] + in[i]) ), 64-wide ----------
template <int SQUARE>
__global__ __launch_bounds__(256) void hop64_kernel(const __half* __restrict__ in_h,
                                                    const float* __restrict__ dinv,
                                                    const int* __restrict__ rbeg,
                                                    const int* __restrict__ rend,
                                                    const int* __restrict__ csr,
                                                    __half* __restrict__ out_h, int N) {
    const int tid = threadIdx.x;
    const int w = tid >> 6, lane = tid & 63;
    const int i = blockIdx.x * 4 + w;
    if (i >= N) return;                           // wave-uniform; no barriers
    const int sub = lane >> 3;
    const int q = lane & 7;
    const uint4* X = (const uint4*)in_h;

    __half2 a[4];
    a[0] = __float2half2_rn(0.f); a[1] = a[0]; a[2] = a[0]; a[3] = a[0];

    int ks = rbeg[i], ke = rend[i];
    gather_row64(a, X, csr, ks, ke, sub, q, N);
    if (sub == 0) acc4(a, X[(size_t)i * RQ8 + q]);   // self term

    a[0] = red8(a[0]); a[1] = red8(a[1]); a[2] = red8(a[2]); a[3] = red8(a[3]);

    if (sub == 0) {
        float di = dinv[i];
        float s = SQUARE ? di * di : di;
        union { uint4 u; __half2 h[4]; } r;
        #pragma unroll
        for (int t = 0; t < 4; ++t) {
            float2 f = __half22float2(a[t]);
            r.h[t] = __floats2half2_rn(s * f.x, s * f.y);
        }
        ((uint4*)out_h)[(size_t)i * RQ8 + q] = r.u;
    }
}

// ---------- hop2 fused with bias + log_softmax: out fp32 [N,64] ----------
__global__ __launch_bounds__(256) void hop2cls_kernel(const __half* __restrict__ in_h,
                                                      const float* __restrict__ dinv,
                                                      const int* __restrict__ rbeg,
                                                      const int* __restrict__ rend,
                                                      const int* __restrict__ csr,
                                                      const float* __restrict__ b,
                                                      float* __restrict__ out, int N) {
    const int tid = threadIdx.x;
    const int w = tid >> 6, lane = tid & 63;
    const int i = blockIdx.x * 4 + w;
    if (i >= N) return;
    const int sub = lane >> 3;
    const int q = lane & 7;
    const uint4* X = (const uint4*)in_h;

    float4 b0 = ((const float4*)b)[q * 2];
    float4 b1 = ((const float4*)b)[q * 2 + 1];

    __half2 a[4];
    a[0] = __float2half2_rn(0.f); a[1] = a[0]; a[2] = a[0]; a[3] = a[0];

    int ks = rbeg[i], ke = rend[i];
    gather_row64(a, X, csr, ks, ke, sub, q, N);
    if (sub == 0) acc4(a, X[(size_t)i * RQ8 + q]);   // self term

    a[0] = red8(a[0]); a[1] = red8(a[1]); a[2] = red8(a[2]); a[3] = red8(a[3]);

    if (sub == 0) {                                  // lanes 0..7 hold the 64-class row
        float di = dinv[i];
        float f[8];
        float2 p;
        p = __half22float2(a[0]); f[0] = fmaf(di, p.x, b0.x); f[1] = fmaf(di, p.y, b0.y);
        p = __half22float2(a[1]); f[2] = fmaf(di, p.x, b0.z); f[3] = fmaf(di, p.y, b0.w);
        p = __half22float2(a[2]); f[4] = fmaf(di, p.x, b1.x); f[5] = fmaf(di, p.y, b1.y);
        p = __half22float2(a[3]); f[6] = fmaf(di, p.x, b1.z); f[7] = fmaf(di, p.y, b1.w);
        float m = f[0];
        #pragma unroll
        for (int t = 1; t < 8; ++t) m = fmaxf(m, f[t]);
        m = fmaxf(m, __shfl_xor(m, 1));              // partners stay within lanes 0..7
        m = fmaxf(m, __shfl_xor(m, 2));
        m = fmaxf(m, __shfl_xor(m, 4));
        float se = 0.f;
        #pragma unroll
        for (int t = 0; t < 8; ++t) se += __expf(f[t] - m);
        se += __shfl_xor(se, 1);
        se += __shfl_xor(se, 2);
        se += __shfl_xor(se, 4);
        float ls = m + logf(se);
        float4 o0 = {f[0] - ls, f[1] - ls, f[2] - ls, f[3] - ls};
        float4 o1 = {f[4] - ls, f[5] - ls, f[6] - ls, f[7] - ls};
        float4* op = (float4*)(out + (size_t)i * NCLS);
        op[q * 2] = o0; op[q * 2 + 1] = o1;
    }
}

// ---------- launch ----------

static inline size_t align256(size_t v) { return (v + 255) & ~(size_t)255; }

extern "C" void kernel_launch(void* const* d_in, const int* in_sizes, int n_in,
                              void* d_out, int out_size, void* d_ws, size_t ws_size,
                              hipStream_t stream) {
    const float* x  = (const float*)d_in[0];
    const int*   ei = (const int*)d_in[1];
    const float* W  = (const float*)d_in[2];
    const float* b  = (const float*)d_in[3];
    float* out = (float*)d_out;

    const int N = in_sizes[0] / NFEAT;   // 50000
    const int E = in_sizes[1] / 2;       // 800000
    const int* src = ei;
    const int* dst = ei + E;
    const int NBUCK = (N + 255) >> 8;    // 196 buckets of 256 nodes

    const int CSR_CAP = E + 1792 * NBUCK + 64;   // per-bucket pad slack + overrun slack

    char* ws = (char*)d_ws;
    size_t o = 0;
    int*    h     = (int*)(ws + o);    o += align256((size_t)NBLK * NBUCK * 4);
    int*    btot  = (int*)(ws + o);    o += align256(256 * 4);
    int*    bbase = (int*)(ws + o);    o += align256(257 * 4);
    int2*   bedg  = (int2*)(ws + o);   o += align256((size_t)E * 8);
    int*    csr   = (int*)(ws + o);    o += align256((size_t)CSR_CAP * 4);
    int*    rbeg  = (int*)(ws + o);    o += align256((size_t)N * 4);
    int*    rend  = (int*)(ws + o);    o += align256((size_t)N * 4);
    float*  dinv  = (float*)(ws + o);  o += align256((size_t)N * 4);
    __half* zh    = (__half*)(ws + o); o += align256((size_t)(N + 1) * NCLS * 2);
    __half* y1h   = (__half*)(ws + o); o += align256((size_t)(N + 1) * NCLS * 2);

    const int E4 = (E + 3) / 4;

    hist_kernel<<<NBLK, 256, 0, stream>>>(dst, h, E4, E, NBUCK);
    colscan_kernel<<<NBUCK, 256, 0, stream>>>(h, btot, NBUCK);
    bucket_scan_kernel<<<1, 256, 0, stream>>>(btot, bbase, NBUCK);
    bucket_scatter_kernel<<<NBLK, 256, 0, stream>>>(src, dst, h, bbase, bedg, E4, E, NBUCK);
    drain_kernel<<<NBUCK, 256, 0, stream>>>(bedg, bbase, csr, rbeg, rend, dinv, N);
    gemm_kernel<<<(N + 63) / 64, 512, 0, stream>>>(x, W, dinv, zh, y1h, N);
    hop64_kernel<1><<<(N + 3) / 4, 256, 0, stream>>>(zh, dinv, rbeg, rend, csr, y1h, N);
    hop2cls_kernel<<<(N + 3) / 4, 256, 0, stream>>>(y1h, dinv, rbeg, rend, csr, b, out, N);
}